// Round 2
// baseline (190.872 us; speedup 1.0000x reference)
//
#include <hip/hip_runtime.h>
#include <hip/hip_bf16.h>

#define NROWS 262144
#define KO 64
#define DW 4
#define TROWS (NROWS - DW)   // 262140

using f32x4  = __attribute__((ext_vector_type(4))) float;
using bf16x8 = __attribute__((ext_vector_type(8))) __bf16;

// Pack B into per-lane MFMA fragment order (bf16).
// Fragment (cc, kt): lane l holds B[c = cc*32 + 8*(l>>4) + e][k = kt*16 + (l&15)], e=0..7
// where B[c][k] = B3[k][j][i] = beta[64 + (k*64 + j)*4 + i], i = c>>6, j = c&63.
__global__ void pack_b_kernel(const float* __restrict__ beta, __bf16* __restrict__ bpack) {
  int idx = blockIdx.x * 256 + threadIdx.x;  // 0..2047  (8 cc * 4 kt * 64 lanes)
  if (idx >= 2048) return;
  int lane = idx & 63;
  int kt = (idx >> 6) & 3;
  int cc = idx >> 8;
  int kout = kt * 16 + (lane & 15);
  int cbase = cc * 32 + 8 * (lane >> 4);
  __bf16* dst = bpack + idx * 8;
#pragma unroll
  for (int e = 0; e < 8; ++e) {
    int c = cbase + e;
    int i = c >> 6;
    int j = c & 63;
    dst[e] = (__bf16)beta[KO + (kout * KO + j) * DW + i];
  }
}

// Main: each wave computes a 64(t) x 64(k) tile of lam via 16x16x32 bf16 MFMA,
// K-dim = 256 split into 8 chunks of 32. A streamed from global fp32 (cvt to bf16),
// B frags from the packed table (L1-resident). Epilogue: +beta0, store lam,
// accumulate tgt*log(lam) - lam, block-reduce to fp64 partial.
__launch_bounds__(256, 3)
__global__ void poisson_main_kernel(const float* __restrict__ obs,
                                    const float* __restrict__ beta,
                                    const __bf16* __restrict__ bpack,
                                    float* __restrict__ lam_out,
                                    double* __restrict__ partials) {
  const int wave = threadIdx.x >> 6;
  const int lane = threadIdx.x & 63;
  const int lr = lane & 15;   // A row-in-16 / B,D col-in-16
  const int lg = lane >> 4;   // lane group 0..3
  const int t0 = blockIdx.x * 256 + wave * 64;

  f32x4 acc[4][4];  // [tsub][kt]
#pragma unroll
  for (int ts = 0; ts < 4; ++ts)
#pragma unroll
    for (int kt = 0; kt < 4; ++kt)
      acc[ts][kt] = (f32x4){0.f, 0.f, 0.f, 0.f};

#pragma unroll
  for (int cc = 0; cc < 8; ++cc) {
    const int i = cc >> 1;                  // window shift for this c-chunk
    const int jb = (cc & 1) * 32 + 8 * lg;  // column base within the obs row
    bf16x8 afrag[4];
#pragma unroll
    for (int ts = 0; ts < 4; ++ts) {
      int row = t0 + ts * 16 + lr + i;
      row = row < (NROWS - 1) ? row : (NROWS - 1);  // clamp only affects masked tail rows
      const float* p = obs + row * KO + jb;
      f32x4 f0 = *reinterpret_cast<const f32x4*>(p);
      f32x4 f1 = *reinterpret_cast<const f32x4*>(p + 4);
      bf16x8 av;
      av[0] = (__bf16)f0[0]; av[1] = (__bf16)f0[1];
      av[2] = (__bf16)f0[2]; av[3] = (__bf16)f0[3];
      av[4] = (__bf16)f1[0]; av[5] = (__bf16)f1[1];
      av[6] = (__bf16)f1[2]; av[7] = (__bf16)f1[3];
      afrag[ts] = av;
    }
#pragma unroll
    for (int kt = 0; kt < 4; ++kt) {
      bf16x8 bfrag = *reinterpret_cast<const bf16x8*>(bpack + ((cc * 4 + kt) * 64 + lane) * 8);
#pragma unroll
      for (int ts = 0; ts < 4; ++ts)
        acc[ts][kt] = __builtin_amdgcn_mfma_f32_16x16x32_bf16(afrag[ts], bfrag, acc[ts][kt], 0, 0, 0);
    }
  }

  // Epilogue: D mapping (verified): col = lane&15, row = (lane>>4)*4 + reg
  float part = 0.f;
#pragma unroll
  for (int kt = 0; kt < 4; ++kt) {
    const int kk = kt * 16 + lr;
    const float b0 = beta[kk];
#pragma unroll
    for (int ts = 0; ts < 4; ++ts) {
#pragma unroll
      for (int r = 0; r < 4; ++r) {
        const int t = t0 + ts * 16 + lg * 4 + r;
        const float lam = acc[ts][kt][r] + b0;
        if (t < TROWS) {
          lam_out[t * KO + kk] = lam;
          const float tgt = obs[(t + DW) * KO + kk];
          part += tgt * __logf(lam) - lam;
        }
      }
    }
  }

#pragma unroll
  for (int off = 32; off > 0; off >>= 1)
    part += __shfl_down(part, off, 64);

  __shared__ float wpart[4];
  if (lane == 0) wpart[wave] = part;
  __syncthreads();
  if (threadIdx.x == 0)
    partials[blockIdx.x] = (double)wpart[0] + (double)wpart[1] + (double)wpart[2] + (double)wpart[3];
}

__global__ void reduce_kernel(const double* __restrict__ partials, float* __restrict__ out, int n) {
  __shared__ double sd[256];
  double s = 0.0;
  for (int idx = threadIdx.x; idx < n; idx += 256) s += partials[idx];
  sd[threadIdx.x] = s;
  __syncthreads();
  for (int st = 128; st > 0; st >>= 1) {
    if (threadIdx.x < st) sd[threadIdx.x] += sd[threadIdx.x + st];
    __syncthreads();
  }
  if (threadIdx.x == 0) out[0] = (float)sd[0];
}

extern "C" void kernel_launch(void* const* d_in, const int* in_sizes, int n_in,
                              void* d_out, int out_size, void* d_ws, size_t ws_size,
                              hipStream_t stream) {
  const float* obs  = (const float*)d_in[0];
  const float* beta = (const float*)d_in[1];
  float* out = (float*)d_out;

  __bf16* bpack    = (__bf16*)d_ws;                      // 2048*8 bf16 = 32 KB
  double* partials = (double*)((char*)d_ws + 32768);     // 1024 * 8 B

  hipLaunchKernelGGL(pack_b_kernel, dim3(8), dim3(256), 0, stream, beta, bpack);
  hipLaunchKernelGGL(poisson_main_kernel, dim3(1024), dim3(256), 0, stream,
                     obs, beta, bpack, out + 1, partials);
  hipLaunchKernelGGL(reduce_kernel, dim3(1), dim3(256), 0, stream, partials, out, 1024);
}

// Round 3
// 165.583 us; speedup vs baseline: 1.1527x; 1.1527x over previous
//
#include <hip/hip_runtime.h>
#include <hip/hip_bf16.h>

#define NROWS 262144
#define KO 64
#define DW 4
#define TROWS (NROWS - DW)   // 262140

using f32x4  = __attribute__((ext_vector_type(4))) float;
using bf16x8 = __attribute__((ext_vector_type(8))) __bf16;

// Pack B into per-lane MFMA fragment order (bf16) and zero the loglik slot.
// Fragment (cc, kt): lane l holds B[c = cc*32 + 8*(l>>4) + e][k = kt*16 + (l&15)], e=0..7
// where B[c][k] = B3[k][j][i] = beta[64 + (k*64 + j)*4 + i], i = c>>6, j = c&63.
__global__ void pack_b_kernel(const float* __restrict__ beta, __bf16* __restrict__ bpack,
                              float* __restrict__ out0) {
  int idx = blockIdx.x * 256 + threadIdx.x;  // 0..2047  (8 cc * 4 kt * 64 lanes)
  if (idx == 0) out0[0] = 0.f;
  if (idx >= 2048) return;
  int lane = idx & 63;
  int kt = (idx >> 6) & 3;
  int cc = idx >> 8;
  int kout = kt * 16 + (lane & 15);
  int cbase = cc * 32 + 8 * (lane >> 4);
  __bf16* dst = bpack + idx * 8;
#pragma unroll
  for (int e = 0; e < 8; ++e) {
    int c = cbase + e;
    int i = c >> 6;
    int j = c & 63;
    dst[e] = (__bf16)beta[KO + (kout * KO + j) * DW + i];
  }
}

// Each wave: 32(t) x 64(k) tile via 16x16x32 bf16 MFMA, K=256 in 8 chunks.
// tgt prefetched to registers (bf16) in prologue; epilogue stores row-contiguous
// and accumulates tgt*log(lam)-lam; one fp32 atomicAdd per block.
__launch_bounds__(256, 6)
__global__ void poisson_main_kernel(const float* __restrict__ obs,
                                    const float* __restrict__ beta,
                                    const __bf16* __restrict__ bpack,
                                    float* __restrict__ lam_out,
                                    float* __restrict__ loglik) {
  const int wave = threadIdx.x >> 6;
  const int lane = threadIdx.x & 63;
  const int lr = lane & 15;   // A row-in-16 / B,D col-in-16
  const int lg = lane >> 4;   // lane group 0..3
  const int t0 = blockIdx.x * 128 + wave * 32;

  // A base pointers (row clamp covers only masked tail lanes; offsets i<=3 stay in-bounds)
  const float* pA[2];
#pragma unroll
  for (int ts = 0; ts < 2; ++ts) {
    int rb = t0 + 16 * ts + lr;
    if (rb > NROWS - 4) rb = NROWS - 4;
    pA[ts] = obs + rb * KO + 8 * lg;
  }

  // tgt prefetch: 32 values per lane, packed bf16. Same HBM lines the A-loads
  // will need -> warms L2 instead of a second full obs fetch in the epilogue.
  bf16x8 tgtv[4];
#pragma unroll
  for (int ts = 0; ts < 2; ++ts)
#pragma unroll
    for (int r = 0; r < 4; ++r) {
      int tr = t0 + 16 * ts + 4 * lg + r + DW;
      if (tr > NROWS - 1) tr = NROWS - 1;   // masked lanes only
      const float* q = obs + tr * KO + lr;
#pragma unroll
      for (int kt = 0; kt < 4; ++kt) {
        const int idx = ts * 16 + r * 4 + kt;
        tgtv[idx >> 3][idx & 7] = (__bf16)q[kt * 16];
      }
    }

  float b0v[4];
#pragma unroll
  for (int kt = 0; kt < 4; ++kt) b0v[kt] = beta[kt * 16 + lr];

  const __bf16* pB = bpack + lane * 8;

  f32x4 acc[2][4];  // [tsub][kt]
#pragma unroll
  for (int ts = 0; ts < 2; ++ts)
#pragma unroll
    for (int kt = 0; kt < 4; ++kt)
      acc[ts][kt] = (f32x4){0.f, 0.f, 0.f, 0.f};

#pragma unroll
  for (int cc = 0; cc < 8; ++cc) {
    bf16x8 af[2];
#pragma unroll
    for (int ts = 0; ts < 2; ++ts) {
      const float* p = pA[ts] + (cc >> 1) * KO + (cc & 1) * 32;  // imm offsets < 1 KB
      f32x4 f0 = *reinterpret_cast<const f32x4*>(p);
      f32x4 f1 = *reinterpret_cast<const f32x4*>(p + 4);
      bf16x8 av;
      av[0] = (__bf16)f0[0]; av[1] = (__bf16)f0[1];
      av[2] = (__bf16)f0[2]; av[3] = (__bf16)f0[3];
      av[4] = (__bf16)f1[0]; av[5] = (__bf16)f1[1];
      av[6] = (__bf16)f1[2]; av[7] = (__bf16)f1[3];
      af[ts] = av;
    }
#pragma unroll
    for (int kt = 0; kt < 4; ++kt) {
      bf16x8 bfrag = *reinterpret_cast<const bf16x8*>(pB + (cc * 4 + kt) * 512);
      acc[0][kt] = __builtin_amdgcn_mfma_f32_16x16x32_bf16(af[0], bfrag, acc[0][kt], 0, 0, 0);
      acc[1][kt] = __builtin_amdgcn_mfma_f32_16x16x32_bf16(af[1], bfrag, acc[1][kt], 0, 0, 0);
    }
  }

  // Epilogue: D mapping col = lane&15, row = (lane>>4)*4 + reg.
  // Row-contiguous store order: full 256 B of a lam row dirtied back-to-back.
  float part = 0.f;
#pragma unroll
  for (int ts = 0; ts < 2; ++ts)
#pragma unroll
    for (int r = 0; r < 4; ++r) {
      const int t = t0 + 16 * ts + 4 * lg + r;
      if (t < TROWS) {
        float* po = lam_out + t * KO + lr;
#pragma unroll
        for (int kt = 0; kt < 4; ++kt) {
          const float lam = acc[ts][kt][r] + b0v[kt];
          po[kt * 16] = lam;
          const int idx = ts * 16 + r * 4 + kt;
          part += (float)tgtv[idx >> 3][idx & 7] * __logf(lam) - lam;
        }
      }
    }

#pragma unroll
  for (int off = 32; off > 0; off >>= 1)
    part += __shfl_down(part, off, 64);

  __shared__ float wpart[4];
  if (lane == 0) wpart[wave] = part;
  __syncthreads();
  if (threadIdx.x == 0)
    atomicAdd(loglik, wpart[0] + wpart[1] + wpart[2] + wpart[3]);
}

extern "C" void kernel_launch(void* const* d_in, const int* in_sizes, int n_in,
                              void* d_out, int out_size, void* d_ws, size_t ws_size,
                              hipStream_t stream) {
  const float* obs  = (const float*)d_in[0];
  const float* beta = (const float*)d_in[1];
  float* out = (float*)d_out;

  __bf16* bpack = (__bf16*)d_ws;   // 2048*8 bf16 = 32 KB

  hipLaunchKernelGGL(pack_b_kernel, dim3(8), dim3(256), 0, stream, beta, bpack, out);
  hipLaunchKernelGGL(poisson_main_kernel, dim3(2048), dim3(256), 0, stream,
                     obs, beta, bpack, out + 1, out);
}

// Round 5
// 158.209 us; speedup vs baseline: 1.2065x; 1.0466x over previous
//
#include <hip/hip_runtime.h>
#include <hip/hip_bf16.h>

#define NROWS 262144
#define KO 64
#define DW 4
#define TROWS (NROWS - DW)   // 262140

using f32x4  = __attribute__((ext_vector_type(4))) float;
using bf16x8 = __attribute__((ext_vector_type(8))) __bf16;

// Pack B into per-lane MFMA fragment order (bf16) and zero the loglik slot.
// Fragment (cc, kt): lane l holds B[c = cc*32 + 8*(l>>4) + e][k = kt*16 + (l&15)], e=0..7
// where B[c][k] = B3[k][j][i] = beta[64 + (k*64 + j)*4 + i], i = c>>6, j = c&63.
__global__ void pack_b_kernel(const float* __restrict__ beta, __bf16* __restrict__ bpack,
                              float* __restrict__ out0) {
  int idx = blockIdx.x * 256 + threadIdx.x;  // 0..2047
  if (idx == 0) out0[0] = 0.f;
  if (idx >= 2048) return;
  int lane = idx & 63;
  int kt = (idx >> 6) & 3;
  int cc = idx >> 8;
  int kout = kt * 16 + (lane & 15);
  int cbase = cc * 32 + 8 * (lane >> 4);
  __bf16* dst = bpack + idx * 8;
#pragma unroll
  for (int e = 0; e < 8; ++e) {
    int c = cbase + e;
    int i = c >> 6;
    int j = c & 63;
    dst[e] = (__bf16)beta[KO + (kout * KO + j) * DW + i];
  }
}

// Each wave: 32(t) x 64(k) tile via 16x16x32 bf16 MFMA, K=256 in 8 chunks (cc).
// A-loads manually double-buffered (group = 2 cc, 8 x f32x4 in flight) so the
// VMEM chain is pipelined instead of serialized. tgt read in the epilogue
// (L2-warm from this wave's own A-loads).
__launch_bounds__(256, 3)
__global__ void poisson_main_kernel(const float* __restrict__ obs,
                                    const float* __restrict__ beta,
                                    const __bf16* __restrict__ bpack,
                                    float* __restrict__ lam_out,
                                    float* __restrict__ loglik) {
  const int wave = threadIdx.x >> 6;
  const int lane = threadIdx.x & 63;
  const int lr = lane & 15;   // A row-in-16 / B,D col-in-16
  const int lg = lane >> 4;   // lane group 0..3
  const int t0 = blockIdx.x * 128 + wave * 32;

  // A base pointers (clamp affects only masked tail lanes; +3 rows stay in-bounds)
  const float* pA[2];
#pragma unroll
  for (int ts = 0; ts < 2; ++ts) {
    int rb = t0 + 16 * ts + lr;
    if (rb > NROWS - 4) rb = NROWS - 4;
    pA[ts] = obs + rb * KO + 8 * lg;
  }
  const __bf16* pB = bpack + lane * 8;

  f32x4 acc[2][4];
#pragma unroll
  for (int ts = 0; ts < 2; ++ts)
#pragma unroll
    for (int kt = 0; kt < 4; ++kt)
      acc[ts][kt] = (f32x4){0.f, 0.f, 0.f, 0.f};

  // Double-buffered raw A data. Group g covers cc = 2g, 2g+1.
  // All addresses are pA[ts] + compile-time-constant offsets (< 4 KB).
  f32x4 rbuf[2][8];  // [buf][ccp*4 + ts*2 + half]
#define LOADG(BUF, G) do {                                                  \
    _Pragma("unroll")                                                       \
    for (int ccp = 0; ccp < 2; ++ccp)                                       \
      _Pragma("unroll")                                                     \
      for (int ts = 0; ts < 2; ++ts) {                                      \
        const float* p = pA[ts] + (G) * KO + ccp * 32;                      \
        rbuf[BUF][ccp * 4 + ts * 2 + 0] = *reinterpret_cast<const f32x4*>(p);     \
        rbuf[BUF][ccp * 4 + ts * 2 + 1] = *reinterpret_cast<const f32x4*>(p + 4); \
      }                                                                     \
  } while (0)

  LOADG(0, 0);
#pragma unroll
  for (int g = 0; g < 4; ++g) {
    if (g < 3) LOADG((g + 1) & 1, g + 1);   // issue next group's 8 loads first
#pragma unroll
    for (int ccp = 0; ccp < 2; ++ccp) {
      const int cc = 2 * g + ccp;
      bf16x8 ax[2];
#pragma unroll
      for (int ts = 0; ts < 2; ++ts) {
        f32x4 f0 = rbuf[g & 1][ccp * 4 + ts * 2 + 0];
        f32x4 f1 = rbuf[g & 1][ccp * 4 + ts * 2 + 1];
        bf16x8 av;
        av[0] = (__bf16)f0[0]; av[1] = (__bf16)f0[1];
        av[2] = (__bf16)f0[2]; av[3] = (__bf16)f0[3];
        av[4] = (__bf16)f1[0]; av[5] = (__bf16)f1[1];
        av[6] = (__bf16)f1[2]; av[7] = (__bf16)f1[3];
        ax[ts] = av;
      }
#pragma unroll
      for (int kt = 0; kt < 4; ++kt) {
        bf16x8 bfrag = *reinterpret_cast<const bf16x8*>(pB + (cc * 4 + kt) * 512);
        acc[0][kt] = __builtin_amdgcn_mfma_f32_16x16x32_bf16(ax[0], bfrag, acc[0][kt], 0, 0, 0);
        acc[1][kt] = __builtin_amdgcn_mfma_f32_16x16x32_bf16(ax[1], bfrag, acc[1][kt], 0, 0, 0);
      }
    }
  }
#undef LOADG

  // Epilogue: D mapping col = lane&15, row = (lane>>4)*4 + reg.
  // Quarter-wave writes/reads 64 B contiguous row segments.
  float b0v[4];
#pragma unroll
  for (int kt = 0; kt < 4; ++kt) b0v[kt] = beta[kt * 16 + lr];

  float part = 0.f;
#pragma unroll
  for (int ts = 0; ts < 2; ++ts)
#pragma unroll
    for (int r = 0; r < 4; ++r) {
      const int t = t0 + 16 * ts + 4 * lg + r;
      if (t < TROWS) {
        float* po = lam_out + t * KO + lr;
        const float* ptg = obs + (t + DW) * KO + lr;   // L2-warm (A-loads touched it)
#pragma unroll
        for (int kt = 0; kt < 4; ++kt) {
          const float lam = acc[ts][kt][r] + b0v[kt];
          po[kt * 16] = lam;
          part += ptg[kt * 16] * __logf(lam) - lam;
        }
      }
    }

#pragma unroll
  for (int off = 32; off > 0; off >>= 1)
    part += __shfl_down(part, off, 64);

  __shared__ float wpart[4];
  if (lane == 0) wpart[wave] = part;
  __syncthreads();
  if (threadIdx.x == 0)
    atomicAdd(loglik, wpart[0] + wpart[1] + wpart[2] + wpart[3]);
}

extern "C" void kernel_launch(void* const* d_in, const int* in_sizes, int n_in,
                              void* d_out, int out_size, void* d_ws, size_t ws_size,
                              hipStream_t stream) {
  const float* obs  = (const float*)d_in[0];
  const float* beta = (const float*)d_in[1];
  float* out = (float*)d_out;

  __bf16* bpack = (__bf16*)d_ws;   // 2048*8 bf16 = 32 KB

  hipLaunchKernelGGL(pack_b_kernel, dim3(8), dim3(256), 0, stream, beta, bpack, out);
  hipLaunchKernelGGL(poisson_main_kernel, dim3(2048), dim3(256), 0, stream,
                     obs, beta, bpack, out + 1, out);
}

// Round 6
// 139.676 us; speedup vs baseline: 1.3665x; 1.1327x over previous
//
#include <hip/hip_runtime.h>
#include <hip/hip_bf16.h>

#define NROWS 262144
#define KO 64
#define DW 4
#define TROWS (NROWS - DW)   // 262140

#define AROWS 136            // staged obs rows per block (128 tile + 4 window + pad)
#define ACHUNKS (AROWS * 16) // 16B chunks per block = 2176

using f32x4  = __attribute__((ext_vector_type(4))) float;
using bf16x8 = __attribute__((ext_vector_type(8))) __bf16;

typedef const __attribute__((address_space(1))) void* gas_ptr;
typedef __attribute__((address_space(3))) void* las_ptr;

// Pack B into per-lane MFMA fragment order (bf16) and zero the loglik slot.
// Fragment (cc, kt): lane l holds B[c = cc*32 + 8*(l>>4) + e][k = kt*16 + (l&15)], e=0..7
// where B[c][k] = B3[k][j][i] = beta[64 + (k*64 + j)*4 + i], i = c>>6, j = c&63.
__global__ void pack_b_kernel(const float* __restrict__ beta, __bf16* __restrict__ bpack,
                              float* __restrict__ out0) {
  int idx = blockIdx.x * 256 + threadIdx.x;  // 0..2047
  if (idx == 0) out0[0] = 0.f;
  if (idx >= 2048) return;
  int lane = idx & 63;
  int kt = (idx >> 6) & 3;
  int cc = idx >> 8;
  int kout = kt * 16 + (lane & 15);
  int cbase = cc * 32 + 8 * (lane >> 4);
  __bf16* dst = bpack + idx * 8;
#pragma unroll
  for (int e = 0; e < 8; ++e) {
    int c = cbase + e;
    int i = c >> 6;
    int j = c & 63;
    dst[e] = (__bf16)beta[KO + (kout * KO + j) * DW + i];
  }
}

// Block tile = 128 t-rows. obs rows [t0, t0+136) staged to LDS by global_load_lds
// DMA (no VGPR round-trip -> compiler can't serialize the pipeline). LDS layout is
// XOR-swizzled (byte ^= (row&7)<<4) via pre-swizzled GLOBAL source addresses
// (linear LDS dest, rule #21). A-fragments and tgt both read from LDS.
__launch_bounds__(256, 4)
__global__ void poisson_main_kernel(const float* __restrict__ obs,
                                    const float* __restrict__ beta,
                                    const __bf16* __restrict__ bpack,
                                    float* __restrict__ lam_out,
                                    float* __restrict__ loglik) {
  __shared__ float aLds[AROWS * KO];   // 34816 B
  const int tid  = threadIdx.x;
  const int wave = tid >> 6;
  const int lane = tid & 63;
  const int lr = lane & 15;   // A row-in-16 / B,D col-in-16
  const int lg = lane >> 4;   // lane group 0..3
  const int t0 = blockIdx.x * 128;

  // ---- stage: 2176 x 16B chunks, swizzled source, linear LDS dest ----
#pragma unroll
  for (int it = 0; it < 9; ++it) {
    int c = tid + it * 256;
    if (c < ACHUNKS) {                    // cuts at wave granularity on last iter
      int arow = c >> 4;
      int cb   = (c & 15) << 4;           // linear byte-in-row
      int row  = t0 + arow;
      if (row > NROWS - 1) row = NROWS - 1;
      const float* src = obs + row * KO + ((cb ^ ((arow & 7) << 4)) >> 2);
      __builtin_amdgcn_global_load_lds((gas_ptr)src,
          (las_ptr)(aLds + (it * 256 + wave * 64) * 4), 16, 0, 0);
    }
  }

  // independent of LDS: B pointer, beta0, acc init
  const __bf16* pB = bpack + lane * 8;
  float b0v[4];
#pragma unroll
  for (int kt = 0; kt < 4; ++kt) b0v[kt] = beta[kt * 16 + lr];

  f32x4 acc[2][4];
#pragma unroll
  for (int ts = 0; ts < 2; ++ts)
#pragma unroll
    for (int kt = 0; kt < 4; ++kt)
      acc[ts][kt] = (f32x4){0.f, 0.f, 0.f, 0.f};

  asm volatile("s_waitcnt vmcnt(0)" ::: "memory");
  __syncthreads();

  // ---- main loop: A frags from LDS (swizzled ds_read_b128 x2), B from global ----
  const int rowb = 32 * wave + lr;
#pragma unroll
  for (int cc = 0; cc < 8; ++cc) {
    const int i  = cc >> 1;
    const int sw = ((lr + i) & 7) << 4;             // byte swizzle for this lane's rows
    const int cb = (cc & 1) * 128 + 32 * lg;        // linear byte col base
    bf16x8 ax[2];
#pragma unroll
    for (int ts = 0; ts < 2; ++ts) {
      const char* base = (const char*)aLds + (rowb + 16 * ts + i) * 256;
      f32x4 f0 = *reinterpret_cast<const f32x4*>(base + ((cb +  0) ^ sw));
      f32x4 f1 = *reinterpret_cast<const f32x4*>(base + ((cb + 16) ^ sw));
      bf16x8 av;
      av[0] = (__bf16)f0[0]; av[1] = (__bf16)f0[1];
      av[2] = (__bf16)f0[2]; av[3] = (__bf16)f0[3];
      av[4] = (__bf16)f1[0]; av[5] = (__bf16)f1[1];
      av[6] = (__bf16)f1[2]; av[7] = (__bf16)f1[3];
      ax[ts] = av;
    }
#pragma unroll
    for (int kt = 0; kt < 4; ++kt) {
      bf16x8 bfrag = *reinterpret_cast<const bf16x8*>(pB + (cc * 4 + kt) * 512);
      acc[0][kt] = __builtin_amdgcn_mfma_f32_16x16x32_bf16(ax[0], bfrag, acc[0][kt], 0, 0, 0);
      acc[1][kt] = __builtin_amdgcn_mfma_f32_16x16x32_bf16(ax[1], bfrag, acc[1][kt], 0, 0, 0);
    }
  }

  // ---- epilogue: D mapping col = lane&15, row = (lane>>4)*4 + reg.
  // lam stored to global (64B quarter-wave segments); tgt read from LDS (swizzled).
  float part = 0.f;
#pragma unroll
  for (int ts = 0; ts < 2; ++ts)
#pragma unroll
    for (int r = 0; r < 4; ++r) {
      const int tl = 32 * wave + 16 * ts + 4 * lg + r;  // local t
      const int tg = t0 + tl;                            // global t
      if (tg < TROWS) {
        const int trow = tl + DW;
        const int swt  = (trow & 7) << 4;
        const char* tb = (const char*)aLds + trow * 256;
        float* po = lam_out + tg * KO + lr;
#pragma unroll
        for (int kt = 0; kt < 4; ++kt) {
          const float lam = acc[ts][kt][r] + b0v[kt];
          po[kt * 16] = lam;
          const float tgt = *reinterpret_cast<const float*>(tb + (((kt * 16 + lr) * 4) ^ swt));
          part += tgt * __logf(lam) - lam;
        }
      }
    }

#pragma unroll
  for (int off = 32; off > 0; off >>= 1)
    part += __shfl_down(part, off, 64);

  __shared__ float wpart[4];
  if (lane == 0) wpart[wave] = part;
  __syncthreads();
  if (threadIdx.x == 0)
    atomicAdd(loglik, wpart[0] + wpart[1] + wpart[2] + wpart[3]);
}

extern "C" void kernel_launch(void* const* d_in, const int* in_sizes, int n_in,
                              void* d_out, int out_size, void* d_ws, size_t ws_size,
                              hipStream_t stream) {
  const float* obs  = (const float*)d_in[0];
  const float* beta = (const float*)d_in[1];
  float* out = (float*)d_out;

  __bf16* bpack = (__bf16*)d_ws;   // 2048*8 bf16 = 32 KB

  hipLaunchKernelGGL(pack_b_kernel, dim3(8), dim3(256), 0, stream, beta, bpack, out);
  hipLaunchKernelGGL(poisson_main_kernel, dim3(2048), dim3(256), 0, stream,
                     obs, beta, bpack, out + 1, out);
}

// Round 9
// 134.482 us; speedup vs baseline: 1.4193x; 1.0386x over previous
//
#include <hip/hip_runtime.h>
#include <hip/hip_bf16.h>

#define NROWS 262144
#define KO 64
#define DW 4
#define TROWS (NROWS - DW)   // 262140

#define AROWS 144            // staged rows per tile buffer (128 + 4 window; padded to 9*256 chunks)
#define TPB 4                // tiles per block

using f32x4  = __attribute__((ext_vector_type(4))) float;
using bf16x8 = __attribute__((ext_vector_type(8))) __bf16;

typedef const __attribute__((address_space(1))) void* gas_ptr;
typedef __attribute__((address_space(3))) void* las_ptr;

// Pack B into per-lane MFMA fragment order (bf16) and zero the loglik slot.
// Fragment (cc, kt): lane l holds B[c = cc*32 + 8*(l>>4) + e][k = kt*16 + (l&15)], e=0..7
// where B[c][k] = B3[k][j][i] = beta[64 + (k*64 + j)*4 + i], i = c>>6, j = c&63.
__global__ void pack_b_kernel(const float* __restrict__ beta, __bf16* __restrict__ bpack,
                              float* __restrict__ out0) {
  int idx = blockIdx.x * 256 + threadIdx.x;  // 0..2047
  if (idx == 0) out0[0] = 0.f;
  if (idx >= 2048) return;
  int lane = idx & 63;
  int kt = (idx >> 6) & 3;
  int cc = idx >> 8;
  int kout = kt * 16 + (lane & 15);
  int cbase = cc * 32 + 8 * (lane >> 4);
  __bf16* dst = bpack + idx * 8;
#pragma unroll
  for (int e = 0; e < 8; ++e) {
    int c = cbase + e;
    int i = c >> 6;
    int j = c & 63;
    dst[e] = (__bf16)beta[KO + (kout * KO + j) * DW + i];
  }
}

// Persistent block: 4 consecutive 128-row tiles, double-buffered global_load_lds
// staging with counted vmcnt (T3/T4): stage(u+1) -> vmcnt(9) -> barrier ->
// compute(u) -> barrier. LDS XOR-swizzled via pre-swizzled GLOBAL source
// (linear DMA dest, rule #21). A-fragments and tgt both read from LDS.
__launch_bounds__(256, 2)
__global__ void poisson_main_kernel(const float* __restrict__ obs,
                                    const float* __restrict__ beta,
                                    const __bf16* __restrict__ bpack,
                                    float* __restrict__ lam_out,
                                    float* __restrict__ loglik) {
  __shared__ float aLds[2][AROWS * KO];   // 2 x 36864 B
  __shared__ float wpart[4];
  const int tid  = threadIdx.x;
  const int wave = tid >> 6;
  const int lane = tid & 63;
  const int lr = lane & 15;   // A row-in-16 / B,D col-in-16
  const int lg = lane >> 4;   // lane group 0..3
  const int tb0 = blockIdx.x * (TPB * 128);

  // 9 DMA chunks per thread per tile (2304 = 9*256 exactly -> uniform vmcnt).
#define STAGE(BUF, U) do {                                                    \
    _Pragma("unroll")                                                         \
    for (int it = 0; it < 9; ++it) {                                          \
      int c = tid + it * 256;                                                 \
      int arow = c >> 4;                                                      \
      int cb = (c & 15) << 4;                                                 \
      int row = tb0 + (U) * 128 + arow;                                       \
      row = row < NROWS - 1 ? row : NROWS - 1;                                \
      const float* src = obs + row * KO + ((cb ^ ((arow & 7) << 4)) >> 2);    \
      __builtin_amdgcn_global_load_lds((gas_ptr)src,                          \
          (las_ptr)(&aLds[BUF][0] + (it * 256 + wave * 64) * 4), 16, 0, 0);   \
    }                                                                         \
  } while (0)

  const __bf16* pB = bpack + lane * 8;
  float b0v[4];
#pragma unroll
  for (int kt = 0; kt < 4; ++kt) b0v[kt] = beta[kt * 16 + lr];

  float part = 0.f;
  STAGE(0, 0);

#pragma unroll
  for (int u = 0; u < TPB; ++u) {
    if (u < TPB - 1) {
      STAGE((u + 1) & 1, u + 1);                      // next tile's 9 loads in flight
      asm volatile("s_waitcnt vmcnt(9)" ::: "memory");  // current tile's loads done
    } else {
      asm volatile("s_waitcnt vmcnt(0)" ::: "memory");
    }
    __builtin_amdgcn_s_barrier();

    const char* bufc = (const char*)&aLds[u & 1][0];
    f32x4 acc[2][4];
#pragma unroll
    for (int ts = 0; ts < 2; ++ts)
#pragma unroll
      for (int kt = 0; kt < 4; ++kt)
        acc[ts][kt] = (f32x4){0.f, 0.f, 0.f, 0.f};

    const int rowb = 32 * wave + lr;
#pragma unroll
    for (int cc = 0; cc < 8; ++cc) {
      const int i  = cc >> 1;
      const int sw = ((lr + i) & 7) << 4;
      const int cb = (cc & 1) * 128 + 32 * lg;
      bf16x8 ax[2];
#pragma unroll
      for (int ts = 0; ts < 2; ++ts) {
        const char* base = bufc + (rowb + 16 * ts + i) * 256;
        f32x4 f0 = *reinterpret_cast<const f32x4*>(base + ((cb +  0) ^ sw));
        f32x4 f1 = *reinterpret_cast<const f32x4*>(base + ((cb + 16) ^ sw));
        bf16x8 av;
        av[0] = (__bf16)f0[0]; av[1] = (__bf16)f0[1];
        av[2] = (__bf16)f0[2]; av[3] = (__bf16)f0[3];
        av[4] = (__bf16)f1[0]; av[5] = (__bf16)f1[1];
        av[6] = (__bf16)f1[2]; av[7] = (__bf16)f1[3];
        ax[ts] = av;
      }
#pragma unroll
      for (int kt = 0; kt < 4; ++kt) {
        bf16x8 bfrag = *reinterpret_cast<const bf16x8*>(pB + (cc * 4 + kt) * 512);
        acc[0][kt] = __builtin_amdgcn_mfma_f32_16x16x32_bf16(ax[0], bfrag, acc[0][kt], 0, 0, 0);
        acc[1][kt] = __builtin_amdgcn_mfma_f32_16x16x32_bf16(ax[1], bfrag, acc[1][kt], 0, 0, 0);
      }
    }

    // Epilogue: D mapping col = lane&15, row = (lane>>4)*4 + reg.
    const int t0 = tb0 + u * 128;
#pragma unroll
    for (int ts = 0; ts < 2; ++ts)
#pragma unroll
      for (int r = 0; r < 4; ++r) {
        const int tl = 32 * wave + 16 * ts + 4 * lg + r;
        const int tg = t0 + tl;
        if (tg < TROWS) {
          const int trow = tl + DW;
          const int swt  = (trow & 7) << 4;
          const char* tb = bufc + trow * 256;
          float* po = lam_out + tg * KO + lr;
#pragma unroll
          for (int kt = 0; kt < 4; ++kt) {
            const float lam = acc[ts][kt][r] + b0v[kt];
            po[kt * 16] = lam;
            const float tgt = *reinterpret_cast<const float*>(tb + (((kt * 16 + lr) * 4) ^ swt));
            part += tgt * __logf(lam) - lam;
          }
        }
      }

    __builtin_amdgcn_s_barrier();   // buf[u&1] free before it's re-staged (iter u+2)
  }
#undef STAGE

#pragma unroll
  for (int off = 32; off > 0; off >>= 1)
    part += __shfl_down(part, off, 64);

  if (lane == 0) wpart[wave] = part;
  __syncthreads();
  if (tid == 0)
    atomicAdd(loglik, wpart[0] + wpart[1] + wpart[2] + wpart[3]);
}

extern "C" void kernel_launch(void* const* d_in, const int* in_sizes, int n_in,
                              void* d_out, int out_size, void* d_ws, size_t ws_size,
                              hipStream_t stream) {
  const float* obs  = (const float*)d_in[0];
  const float* beta = (const float*)d_in[1];
  float* out = (float*)d_out;

  __bf16* bpack = (__bf16*)d_ws;   // 2048*8 bf16 = 32 KB

  hipLaunchKernelGGL(pack_b_kernel, dim3(8), dim3(256), 0, stream, beta, bpack, out);
  hipLaunchKernelGGL(poisson_main_kernel, dim3(512), dim3(256), 0, stream,
                     obs, beta, bpack, out + 1, out);
}